// Round 7
// baseline (86.802 us; speedup 1.0000x reference)
//
#include <hip/hip_runtime.h>
#include <math.h>

// Problem constants (reference: N=8192, D=200, k=100)
#define NN 8192
#define DD 200
#define KK 100

// s = b_i + e_j histogram grid: 1024 bins over [-8, 8), width 2^-6 (exact fp)
#define NBINS 1024
#define HSCALE 64.0f
#define BINW 0.015625f
#define CAND_CAP 4096
#define ROW_CAP 1024
#define COL_CAP 1024
#define NBLK 256

// ws word offsets. DONE starts at the harness poison value (0xAAAAAAAA) —
// the harness re-poisons d_ws to 0xAA before EVERY launch (documented
// contract), so the last of NBLK one-per-block atomicAdds observes
// old == 0xAAAAAAAA + NBLK - 1. No memset dispatch needed.
#define OFF_B 0
#define OFF_E 8192
#define OFF_DONE 16384
#define DONE_SENTINEL (0xAAAAAAAAu + (unsigned)(NBLK - 1))

__global__ __launch_bounds__(1024) void k_all(const float* __restrict__ G,
                                              const float* __restrict__ wb,
                                              const float* __restrict__ we,
                                              float* __restrict__ wsf,
                                              unsigned* __restrict__ wsu,
                                              float* __restrict__ out) {
    __shared__ float    b_s[NN];          // 32 KB
    __shared__ float    e_s[NN];          // 32 KB
    __shared__ float    cv[CAND_CAP];     // 16 KB
    __shared__ unsigned ci[CAND_CAP];     // 16 KB
    __shared__ unsigned sfx[NBINS];       // hist_e -> suffix sums (in place)
    __shared__ unsigned hbl[NBINS];       // hist_b
    __shared__ int      rows_s[ROW_CAP];
    __shared__ float    rowb_s[ROW_CAP];
    __shared__ int      cols_s[COL_CAP];
    __shared__ float    cole_s[COL_CAP];
    __shared__ float    fr_sb[16], fr_se[16], fr_em[16], fr_bm[16];
    __shared__ unsigned wred[16], wtail_s[16];
    __shared__ unsigned nrows_s, ncols_s, ncand_s, last_s;
    __shared__ int      lo_s;
    __shared__ float    sums_s[4];        // sb, se, emax, bmax

    int tid = threadIdx.x, wave = tid >> 6, lane = tid & 63;

    // ---- Phase 1: 2 rows per wave (256 blocks x 16 waves x 2 = 8192 rows).
    int row0 = blockIdx.x * 32 + (wave << 1);
#pragma unroll
    for (int i = 0; i < 2; ++i) {
        int row = row0 + i;
        float pb = 0.f, pe = 0.f;
        if (lane < 50) {
            float4 g = ((const float4*)(G + (size_t)row * DD))[lane];
            float4 B = ((const float4*)wb)[lane];
            float4 E = ((const float4*)we)[lane];
            pb = fmaf(g.x, B.x, fmaf(g.y, B.y, fmaf(g.z, B.z, g.w * B.w)));
            pe = fmaf(g.x, E.x, fmaf(g.y, E.y, fmaf(g.z, E.z, g.w * E.w)));
        }
        for (int off = 32; off; off >>= 1) {
            pb += __shfl_xor(pb, off, 64);
            pe += __shfl_xor(pe, off, 64);
        }
        if (lane == 0) { wsf[OFF_B + row] = pb; wsf[OFF_E + row] = pe; }
    }
    __syncthreads();
    if (tid == 0) {
        __threadfence();                              // release b/e stores
        last_s = atomicAdd(wsu + OFF_DONE, 1u);       // device-scope (m20)
    }
    __syncthreads();
    if (last_s != DONE_SENTINEL) return;              // only last block continues
    __threadfence();                                  // acquire all blocks' stores

    // ---- Tail (one block): stage b,e (float4) + hists + fused reductions.
    sfx[tid] = 0u; hbl[tid] = 0u;
    if (tid == 0) { nrows_s = 0u; ncols_s = 0u; ncand_s = 0u; lo_s = 0; }
    __syncthreads();
    float leb = 0.f, lee = 0.f, lem = -1e30f, lbm = -1e30f;
    const float4* b4 = (const float4*)(wsf + OFF_B);
    const float4* e4 = (const float4*)(wsf + OFF_E);
    for (int i = tid; i < NN / 4; i += 1024) {        // 2 iterations
        float4 bv = b4[i], ev = e4[i];
        ((float4*)b_s)[i] = bv;
        ((float4*)e_s)[i] = ev;
        leb += expf(bv.x) + expf(bv.y) + expf(bv.z) + expf(bv.w);
        lee += expf(ev.x) + expf(ev.y) + expf(ev.z) + expf(ev.w);
        lbm = fmaxf(lbm, fmaxf(fmaxf(bv.x, bv.y), fmaxf(bv.z, bv.w)));
        lem = fmaxf(lem, fmaxf(fmaxf(ev.x, ev.y), fmaxf(ev.z, ev.w)));
        int p;
        p = (int)fmaf(bv.x, HSCALE, 512.f); atomicAdd(&hbl[min(max(p,0),NBINS-1)], 1u);
        p = (int)fmaf(bv.y, HSCALE, 512.f); atomicAdd(&hbl[min(max(p,0),NBINS-1)], 1u);
        p = (int)fmaf(bv.z, HSCALE, 512.f); atomicAdd(&hbl[min(max(p,0),NBINS-1)], 1u);
        p = (int)fmaf(bv.w, HSCALE, 512.f); atomicAdd(&hbl[min(max(p,0),NBINS-1)], 1u);
        p = (int)fmaf(ev.x, HSCALE, 512.f); atomicAdd(&sfx[min(max(p,0),NBINS-1)], 1u);
        p = (int)fmaf(ev.y, HSCALE, 512.f); atomicAdd(&sfx[min(max(p,0),NBINS-1)], 1u);
        p = (int)fmaf(ev.z, HSCALE, 512.f); atomicAdd(&sfx[min(max(p,0),NBINS-1)], 1u);
        p = (int)fmaf(ev.w, HSCALE, 512.f); atomicAdd(&sfx[min(max(p,0),NBINS-1)], 1u);
    }
    for (int off = 32; off; off >>= 1) {
        leb += __shfl_xor(leb, off, 64);
        lee += __shfl_xor(lee, off, 64);
        lem = fmaxf(lem, __shfl_xor(lem, off, 64));
        lbm = fmaxf(lbm, __shfl_xor(lbm, off, 64));
    }
    if (lane == 0) { fr_sb[wave] = leb; fr_se[wave] = lee; fr_em[wave] = lem; fr_bm[wave] = lbm; }
    __syncthreads();
    if (tid == 0) {
        float a = 0.f, b = 0.f, c = -1e30f, d = -1e30f;
        for (int i = 0; i < 16; ++i) {
            a += fr_sb[i]; b += fr_se[i];
            c = fmaxf(c, fr_em[i]); d = fmaxf(d, fr_bm[i]);
        }
        sums_s[0] = a; sums_s[1] = b; sums_s[2] = c; sums_s[3] = d;
    }

    // ---- Suffix-sum hist_e in place: intra-wave shfl_down + wave tails.
    unsigned v = sfx[tid];
    for (int off = 1; off < 64; off <<= 1) {
        unsigned t = __shfl_down(v, off, 64);
        if (lane + off < 64) v += t;
    }
    if (lane == 0) wtail_s[wave] = v;
    __syncthreads();
    if (tid == 0) {
        unsigned acc = 0, tails[16];
        for (int w = 15; w >= 0; --w) { tails[w] = acc; acc += wtail_s[w]; }
        for (int w = 0; w < 16; ++w) wtail_s[w] = tails[w];
    }
    __syncthreads();
    sfx[tid] = v + wtail_s[wave];
    __syncthreads();

    // ---- 16-ary descent for largest t with cnt(t) >= 2*KK (same exact
    // integer math and t* as R2..R6, all absmax 0).
    const unsigned TARGET = 2u * KK;
    int chunk = 64;
    for (int round = 0; round < 2; ++round) {
        int t = lo_s + (wave + 1) * chunk;
        unsigned c = 0;
        for (int k = 0; k < 16; ++k) {
            int p = lane + (k << 6);
            int idx = t + 512 - p;
            unsigned sv = (idx <= 0) ? sfx[0] : ((idx > NBINS - 1) ? 0u : sfx[idx]);
            c += hbl[p] * sv;
        }
        for (int off = 32; off; off >>= 1) c += __shfl_xor(c, off, 64);
        if (lane == 0) wred[wave] = c;
        __syncthreads();
        if (tid == 0) {
            for (int w = 15; w >= 0; --w)
                if (wred[w] >= TARGET) { lo_s += (w + 1) * chunk; break; }
        }
        __syncthreads();
        chunk >>= 4;
    }
    {
        int t = lo_s + wave + 1;
        if (wave < 3) {
            unsigned c = 0;
            for (int k = 0; k < 16; ++k) {
                int p = lane + (k << 6);
                int idx = t + 512 - p;
                unsigned sv = (idx <= 0) ? sfx[0] : ((idx > NBINS - 1) ? 0u : sfx[idx]);
                c += hbl[p] * sv;
            }
            for (int off = 32; off; off >>= 1) c += __shfl_xor(c, off, 64);
            if (lane == 0) wred[wave] = c;
        }
        __syncthreads();
        if (tid == 0) {
            for (int w = 2; w >= 0; --w)
                if (wred[w] >= TARGET) { lo_s += w + 1; break; }
        }
        __syncthreads();
    }
    float thr = -8.0f + (float)(lo_s - 1) * BINW;     // one-bin safety margin
    float emax = sums_s[2], bmax = sums_s[3];

    // ---- Row/column candidate lists (conservative supersets).
    for (int i = tid; i < NN; i += 1024) {
        float bv = b_s[i];
        if (bv + emax >= thr) {
            unsigned pos = atomicAdd(&nrows_s, 1u);
            if (pos < ROW_CAP) { rows_s[pos] = i; rowb_s[pos] = bv; }
        }
        float ev = e_s[i];
        if (ev + bmax >= thr) {
            unsigned pos = atomicAdd(&ncols_s, 1u);
            if (pos < COL_CAP) { cols_s[pos] = i; cole_s[pos] = ev; }
        }
    }
    __syncthreads();
    int nr = (int)min(nrows_s, (unsigned)ROW_CAP);
    int nc = (int)min(ncols_s, (unsigned)COL_CAP);

    // ---- Pair scan over nr x nc candidate grid, upper triangle (j >= r).
    int tot = nr * nc;
    for (int idx = tid; idx < tot; idx += 1024) {
        int ri = idx / nc, cj = idx - ri * nc;
        int r = rows_s[ri], j = cols_s[cj];
        if (j < r) continue;
        float s = rowb_s[ri] + cole_s[cj];
        if (s >= thr) {
            unsigned pos = atomicAdd(&ncand_s, 1u);
            if (pos < CAND_CAP) {
                cv[pos] = s;
                ci[pos] = ((unsigned)r << 13) | (unsigned)j;
            }
        }
    }
    __syncthreads();

    // ---- Rank-based top-100 (jax order: value desc, flat index asc).
    unsigned M = min(ncand_s, (unsigned)CAND_CAP);
    float inv_den = 1.0f / (sums_s[0] * sums_s[1]);
    for (unsigned c2 = tid; c2 < M; c2 += 1024) {
        float vv = cv[c2];
        unsigned fi = ci[c2];
        int rank = 0;
        for (unsigned m = 0; m < M; ++m) {
            float vm = cv[m];
            rank += (vm > vv) || (vm == vv && ci[m] < fi);
        }
        if (rank < KK) {
            out[2 * rank]     = (float)(fi >> 13);
            out[2 * rank + 1] = (float)(fi & 8191u);
            out[200 + rank]   = expf(vv) * inv_den;
        }
    }
}

extern "C" void kernel_launch(void* const* d_in, const int* in_sizes, int n_in,
                              void* d_out, int out_size, void* d_ws, size_t ws_size,
                              hipStream_t stream) {
    const float* G  = (const float*)d_in[0];
    const float* wb = (const float*)d_in[1];
    const float* we = (const float*)d_in[2];
    float* out = (float*)d_out;
    float* wsf = (float*)d_ws;
    unsigned* wsu = (unsigned*)d_ws;

    hipLaunchKernelGGL(k_all, dim3(NBLK), dim3(1024), 0, stream,
                       G, wb, we, wsf, wsu, out);
}

// Round 8
// 78.831 us; speedup vs baseline: 1.1011x; 1.1011x over previous
//
#include <hip/hip_runtime.h>
#include <math.h>

// Problem constants (reference: N=8192, D=200, k=100)
#define NN 8192
#define DD 200
#define KK 100

// s = b_i + e_j histogram grid: 1024 bins over [-8, 8), width 2^-6 (exact fp)
#define NBINS 1024
#define HSCALE 64.0f
#define BINW 0.015625f
#define CAND_CAP 4096
#define ROW_CAP 1024
#define COL_CAP 1024

// ws layout (4-byte word offsets): only b and e cross the kernel boundary.
#define OFF_B 0
#define OFF_E 8192

// K1: b[i] = G[i,:]·wb, e[i] = G[i,:]·we. One wave per row; 50 lanes × float4.
// 2048 light blocks — scheduler-friendly; kernel boundary provides the
// cross-XCD visibility for k_tail (R7 showed fusing this costs +7 µs).
__global__ __launch_bounds__(256) void k_be(const float* __restrict__ G,
                                            const float* __restrict__ wb,
                                            const float* __restrict__ we,
                                            float* __restrict__ wsf) {
    int gid = blockIdx.x * 256 + threadIdx.x;
    int row = gid >> 6;
    int lane = gid & 63;
    float pb = 0.f, pe = 0.f;
    if (lane < 50) {
        float4 g = ((const float4*)(G + (size_t)row * DD))[lane];
        float4 B = ((const float4*)wb)[lane];
        float4 E = ((const float4*)we)[lane];
        pb = fmaf(g.x, B.x, fmaf(g.y, B.y, fmaf(g.z, B.z, g.w * B.w)));
        pe = fmaf(g.x, E.x, fmaf(g.y, E.y, fmaf(g.z, E.z, g.w * E.w)));
    }
    for (int off = 32; off; off >>= 1) {
        pb += __shfl_xor(pb, off, 64);
        pe += __shfl_xor(pe, off, 64);
    }
    if (lane == 0) { wsf[OFF_B + row] = pb; wsf[OFF_E + row] = pe; }
}

// K2: single block, 1024 threads, everything in LDS (R6 champion + float4 staging).
__global__ __launch_bounds__(1024) void k_tail(const float* __restrict__ wsf,
                                               float* __restrict__ out) {
    __shared__ float    b_s[NN];          // 32 KB
    __shared__ float    e_s[NN];          // 32 KB
    __shared__ float    cv[CAND_CAP];     // 16 KB
    __shared__ unsigned ci[CAND_CAP];     // 16 KB
    __shared__ unsigned sfx[NBINS];       // hist_e -> suffix sums (in place)
    __shared__ unsigned hbl[NBINS];       // hist_b
    __shared__ int      rows_s[ROW_CAP];
    __shared__ float    rowb_s[ROW_CAP];
    __shared__ int      cols_s[COL_CAP];
    __shared__ float    cole_s[COL_CAP];
    __shared__ float    fr_sb[16], fr_se[16], fr_em[16], fr_bm[16];
    __shared__ unsigned wred[16], wtail_s[16];
    __shared__ unsigned nrows_s, ncols_s, ncand_s;
    __shared__ int      lo_s;
    __shared__ float    sums_s[4];        // sb, se, emax, bmax

    int tid = threadIdx.x, wave = tid >> 6, lane = tid & 63;

    sfx[tid] = 0u; hbl[tid] = 0u;
    if (tid == 0) { nrows_s = 0u; ncols_s = 0u; ncand_s = 0u; lo_s = 0; }
    __syncthreads();

    // ---- Stage b,e (float4) + LDS-atomic hists + 4 fused wave reductions.
    float leb = 0.f, lee = 0.f, lem = -1e30f, lbm = -1e30f;
    const float4* b4 = (const float4*)(wsf + OFF_B);
    const float4* e4 = (const float4*)(wsf + OFF_E);
    for (int i = tid; i < NN / 4; i += 1024) {        // 2 iterations
        float4 bv = b4[i], ev = e4[i];
        ((float4*)b_s)[i] = bv;
        ((float4*)e_s)[i] = ev;
        leb += expf(bv.x) + expf(bv.y) + expf(bv.z) + expf(bv.w);
        lee += expf(ev.x) + expf(ev.y) + expf(ev.z) + expf(ev.w);
        lbm = fmaxf(lbm, fmaxf(fmaxf(bv.x, bv.y), fmaxf(bv.z, bv.w)));
        lem = fmaxf(lem, fmaxf(fmaxf(ev.x, ev.y), fmaxf(ev.z, ev.w)));
        int p;
        p = (int)fmaf(bv.x, HSCALE, 512.f); atomicAdd(&hbl[min(max(p,0),NBINS-1)], 1u);
        p = (int)fmaf(bv.y, HSCALE, 512.f); atomicAdd(&hbl[min(max(p,0),NBINS-1)], 1u);
        p = (int)fmaf(bv.z, HSCALE, 512.f); atomicAdd(&hbl[min(max(p,0),NBINS-1)], 1u);
        p = (int)fmaf(bv.w, HSCALE, 512.f); atomicAdd(&hbl[min(max(p,0),NBINS-1)], 1u);
        p = (int)fmaf(ev.x, HSCALE, 512.f); atomicAdd(&sfx[min(max(p,0),NBINS-1)], 1u);
        p = (int)fmaf(ev.y, HSCALE, 512.f); atomicAdd(&sfx[min(max(p,0),NBINS-1)], 1u);
        p = (int)fmaf(ev.z, HSCALE, 512.f); atomicAdd(&sfx[min(max(p,0),NBINS-1)], 1u);
        p = (int)fmaf(ev.w, HSCALE, 512.f); atomicAdd(&sfx[min(max(p,0),NBINS-1)], 1u);
    }
    for (int off = 32; off; off >>= 1) {
        leb += __shfl_xor(leb, off, 64);
        lee += __shfl_xor(lee, off, 64);
        lem = fmaxf(lem, __shfl_xor(lem, off, 64));
        lbm = fmaxf(lbm, __shfl_xor(lbm, off, 64));
    }
    if (lane == 0) { fr_sb[wave] = leb; fr_se[wave] = lee; fr_em[wave] = lem; fr_bm[wave] = lbm; }
    __syncthreads();
    if (tid == 0) {
        float a = 0.f, b = 0.f, c = -1e30f, d = -1e30f;
        for (int i = 0; i < 16; ++i) {
            a += fr_sb[i]; b += fr_se[i];
            c = fmaxf(c, fr_em[i]); d = fmaxf(d, fr_bm[i]);
        }
        sums_s[0] = a; sums_s[1] = b; sums_s[2] = c; sums_s[3] = d;
    }

    // ---- Suffix-sum hist_e in place: intra-wave shfl_down + wave tails.
    unsigned v = sfx[tid];
    for (int off = 1; off < 64; off <<= 1) {
        unsigned t = __shfl_down(v, off, 64);
        if (lane + off < 64) v += t;
    }
    if (lane == 0) wtail_s[wave] = v;
    __syncthreads();
    if (tid == 0) {
        unsigned acc = 0, tails[16];
        for (int w = 15; w >= 0; --w) { tails[w] = acc; acc += wtail_s[w]; }
        for (int w = 0; w < 16; ++w) wtail_s[w] = tails[w];
    }
    __syncthreads();
    sfx[tid] = v + wtail_s[wave];
    __syncthreads();

    // ---- 16-ary descent for largest t with cnt(t) >= 2*KK (same exact
    // integer math and t* as R2..R7, all absmax 0).
    const unsigned TARGET = 2u * KK;
    int chunk = 64;
    for (int round = 0; round < 2; ++round) {
        int t = lo_s + (wave + 1) * chunk;
        unsigned c = 0;
        for (int k = 0; k < 16; ++k) {
            int p = lane + (k << 6);
            int idx = t + 512 - p;
            unsigned sv = (idx <= 0) ? sfx[0] : ((idx > NBINS - 1) ? 0u : sfx[idx]);
            c += hbl[p] * sv;
        }
        for (int off = 32; off; off >>= 1) c += __shfl_xor(c, off, 64);
        if (lane == 0) wred[wave] = c;
        __syncthreads();
        if (tid == 0) {
            for (int w = 15; w >= 0; --w)
                if (wred[w] >= TARGET) { lo_s += (w + 1) * chunk; break; }
        }
        __syncthreads();
        chunk >>= 4;   // 64 -> 4
    }
    {   // bracket is 4 wide: evaluate lo+1..lo+3 with waves 0..2
        int t = lo_s + wave + 1;
        if (wave < 3) {
            unsigned c = 0;
            for (int k = 0; k < 16; ++k) {
                int p = lane + (k << 6);
                int idx = t + 512 - p;
                unsigned sv = (idx <= 0) ? sfx[0] : ((idx > NBINS - 1) ? 0u : sfx[idx]);
                c += hbl[p] * sv;
            }
            for (int off = 32; off; off >>= 1) c += __shfl_xor(c, off, 64);
            if (lane == 0) wred[wave] = c;
        }
        __syncthreads();
        if (tid == 0) {
            for (int w = 2; w >= 0; --w)
                if (wred[w] >= TARGET) { lo_s += w + 1; break; }
        }
        __syncthreads();
    }
    float thr = -8.0f + (float)(lo_s - 1) * BINW;   // one-bin safety margin
    float emax = sums_s[2], bmax = sums_s[3];

    // ---- Row and column candidate lists (conservative supersets).
    for (int i = tid; i < NN; i += 1024) {
        float bv = b_s[i];
        if (bv + emax >= thr) {
            unsigned pos = atomicAdd(&nrows_s, 1u);
            if (pos < ROW_CAP) { rows_s[pos] = i; rowb_s[pos] = bv; }
        }
        float ev = e_s[i];
        if (ev + bmax >= thr) {
            unsigned pos = atomicAdd(&ncols_s, 1u);
            if (pos < COL_CAP) { cols_s[pos] = i; cole_s[pos] = ev; }
        }
    }
    __syncthreads();
    int nr = (int)min(nrows_s, (unsigned)ROW_CAP);
    int nc = (int)min(ncols_s, (unsigned)COL_CAP);

    // ---- Pair scan over nr x nc candidate grid, upper triangle (j >= r).
    int tot = nr * nc;
    for (int idx = tid; idx < tot; idx += 1024) {
        int ri = idx / nc, cj = idx - ri * nc;
        int r = rows_s[ri], j = cols_s[cj];
        if (j < r) continue;
        float s = rowb_s[ri] + cole_s[cj];
        if (s >= thr) {
            unsigned pos = atomicAdd(&ncand_s, 1u);
            if (pos < CAND_CAP) {
                cv[pos] = s;
                ci[pos] = ((unsigned)r << 13) | (unsigned)j;
            }
        }
    }
    __syncthreads();

    // ---- Rank-based top-100 (jax order: value desc, flat index asc).
    unsigned M = min(ncand_s, (unsigned)CAND_CAP);
    float inv_den = 1.0f / (sums_s[0] * sums_s[1]);
    for (unsigned c2 = tid; c2 < M; c2 += 1024) {
        float vv = cv[c2];
        unsigned fi = ci[c2];
        int rank = 0;
        for (unsigned m = 0; m < M; ++m) {
            float vm = cv[m];
            rank += (vm > vv) || (vm == vv && ci[m] < fi);
        }
        if (rank < KK) {
            out[2 * rank]     = (float)(fi >> 13);
            out[2 * rank + 1] = (float)(fi & 8191u);
            out[200 + rank]   = expf(vv) * inv_den;
        }
    }
}

extern "C" void kernel_launch(void* const* d_in, const int* in_sizes, int n_in,
                              void* d_out, int out_size, void* d_ws, size_t ws_size,
                              hipStream_t stream) {
    const float* G  = (const float*)d_in[0];
    const float* wb = (const float*)d_in[1];
    const float* we = (const float*)d_in[2];
    float* out = (float*)d_out;
    float* wsf = (float*)d_ws;

    hipLaunchKernelGGL(k_be, dim3(2048), dim3(256), 0, stream, G, wb, we, wsf);
    hipLaunchKernelGGL(k_tail, dim3(1), dim3(1024), 0, stream, wsf, out);
}